// Round 4
// baseline (820.834 us; speedup 1.0000x reference)
//
#include <hip/hip_runtime.h>
#include <hip/hip_bf16.h>

// ---------------------------------------------------------------------------
// GlobalSAModule: h = MLP3(cat(x,pos)); pooled = segment_max(h);
//                 out = cat(pooled[batch_skip], x_skip)
// Split-bf16 (hi+lo) MFMA GEMMs (absmax 4.9e-4, verified r2/r3).
// r4: BN=256 (halve A-panel L3 re-reads), BK=32 double-buffered 2-phase
// (stage next tile during compute, 1 barrier/K-step), KP1=288.
// ---------------------------------------------------------------------------

typedef __attribute__((ext_vector_type(8))) short bf16x8;
typedef __attribute__((ext_vector_type(16))) float f32x16;

#define GLD_LDS16(src, dst) __builtin_amdgcn_global_load_lds( \
    (const __attribute__((address_space(1))) unsigned int*)(src), \
    (__attribute__((address_space(3))) unsigned int*)(dst), 16, 0, 0)

__device__ __forceinline__ unsigned short f2bf(float f) {
  unsigned int u = __float_as_uint(f);
  unsigned int r = (u + 0x7FFFu + ((u >> 16) & 1u)) >> 16;   // RNE
  return (unsigned short)r;
}
__device__ __forceinline__ float bf2f(unsigned short h) {
  return __uint_as_float(((unsigned int)h) << 16);
}

// --- pack cat(x,pos) -> [N][288] hi/lo bf16 planes --------------------------
__global__ void pack_a1(const float* __restrict__ x, const float* __restrict__ pos,
                        unsigned short* __restrict__ ah, unsigned short* __restrict__ al) {
  const int total = 65536 * 72;                    // 72 quads per 288-row
  for (int idx = blockIdx.x * blockDim.x + threadIdx.x; idx < total;
       idx += gridDim.x * blockDim.x) {
    const int n = idx / 72;
    const int q = idx - n * 72;
    float4 v;
    if (q < 64) {
      v = ((const float4*)x)[(size_t)n * 64 + q];
    } else if (q == 64) {
      v.x = pos[(size_t)n * 3 + 0];
      v.y = pos[(size_t)n * 3 + 1];
      v.z = pos[(size_t)n * 3 + 2];
      v.w = 0.f;
    } else {
      v.x = v.y = v.z = v.w = 0.f;
    }
    ushort4 h, l;
    h.x = f2bf(v.x); l.x = f2bf(v.x - bf2f(h.x));
    h.y = f2bf(v.y); l.y = f2bf(v.y - bf2f(h.y));
    h.z = f2bf(v.z); l.z = f2bf(v.z - bf2f(h.z));
    h.w = f2bf(v.w); l.w = f2bf(v.w - bf2f(h.w));
    *(ushort4*)(ah + (size_t)n * 288 + q * 4) = h;
    *(ushort4*)(al + (size_t)n * 288 + q * 4) = l;
  }
}

// --- pack+transpose weights: W[K][Nout] fp32 -> Wt[Nout][KP] hi/lo ----------
__global__ void pack_w(const float* __restrict__ w, unsigned short* __restrict__ wh,
                       unsigned short* __restrict__ wl, int K, int Nout) {
  const int no = blockIdx.x;
  const int k = threadIdx.x;
  const int KP = blockDim.x;
  float v = (k < K) ? w[(size_t)k * Nout + no] : 0.f;
  unsigned short hi = f2bf(v);
  wh[(size_t)no * KP + k] = hi;
  wl[(size_t)no * KP + k] = f2bf(v - bf2f(hi));
}

__global__ void zero_pool(unsigned int* __restrict__ p) {
  p[blockIdx.x * 1024 + threadIdx.x] = 0u;          // relu outputs >= 0
}

// --- split-bf16 GEMM: C = relu(A @ Wt^T + b), 32x32x16 MFMA -----------------
// 128x256 tile, BK=32, 8 waves (2x4), double-buffered LDS, 1 barrier/K-step.
// Staging: 48 chunks of 1 KiB (16 rows x 64B), 6 per wave; k-slot XOR-swizzle
// (slot = gchunk ^ (row&3)) applied on global source + ds_read (rule #21).
// MODE 0: write C hi/lo planes. MODE 1: fused column-max -> atomicMax(pooled).
template<int KP, int NOUT, int MODE>
__global__ __launch_bounds__(512, 2)
void gemm_split(const unsigned short* __restrict__ gAh, const unsigned short* __restrict__ gAl,
                const unsigned short* __restrict__ gBh, const unsigned short* __restrict__ gBl,
                const float* __restrict__ bias,
                unsigned short* __restrict__ Ch, unsigned short* __restrict__ Cl,
                unsigned int* __restrict__ pooled, const int* __restrict__ batch) {
  constexpr int BM = 128, BN = 256, BK = 32;
  constexpr int NB = NOUT / BN;
  constexpr int KT = KP / BK;
  constexpr int BUF = 24576;                        // shorts per buffer (48 KiB)
  __shared__ unsigned short lds[2 * BUF];           // 96 KiB

  const int nwg = gridDim.x;                        // % 8 == 0 for all uses
  const int bid = (blockIdx.x % 8) * (nwg / 8) + blockIdx.x / 8;  // XCD swizzle
  const int bm = bid / NB, bn = bid % NB;
  const int r0 = bm * BM, c0 = bn * BN;
  const int tid = threadIdx.x;
  const int lane = tid & 63, wid = tid >> 6;        // 8 waves
  const int wm = wid >> 2, wn = wid & 3;            // 2(M) x 4(N) wave grid
  const int al31 = lane & 31, l5 = lane >> 5;
  const int lr = lane >> 2, swz = lane & 3;         // stage: 16 rows x 4 k-slots

  f32x16 acc[2][2] = {};                            // 64 fp32 / lane

  // chunk c in [0,48): [0,8)=Ah, [8,16)=Al rows r0+; [16,32)=Bh, [32,48)=Bl rows c0+
  const unsigned short* src[6];
  int dstoff[6];
  #pragma unroll
  for (int t = 0; t < 6; ++t) {
    const int c = wid * 6 + t;
    const unsigned short* pl; int rowb;
    if (c < 8)       { pl = gAh; rowb = r0 + c * 16; }
    else if (c < 16) { pl = gAl; rowb = r0 + (c - 8) * 16; }
    else if (c < 32) { pl = gBh; rowb = c0 + (c - 16) * 16; }
    else             { pl = gBl; rowb = c0 + (c - 32) * 16; }
    src[t] = pl + (size_t)(rowb + lr) * KP + ((swz ^ (lr & 3)) << 3);
    dstoff[t] = c * 512 + lane * 8;
  }

  // prologue: stage kt=0 into buf0
  #pragma unroll
  for (int t = 0; t < 6; ++t) {
    GLD_LDS16(src[t], lds + dstoff[t]);
    src[t] += BK;
  }
  __syncthreads();

  int cur = 0;
  for (int kt = 0; kt < KT; ++kt) {
    if (kt + 1 < KT) {                              // issue next-tile stage FIRST
      unsigned short* nb = lds + (cur ^ 1) * BUF;
      #pragma unroll
      for (int t = 0; t < 6; ++t) {
        GLD_LDS16(src[t], nb + dstoff[t]);
        src[t] += BK;
      }
    }
    const unsigned short* sA_h = lds + cur * BUF;   // 8 chunks: rows 0..127
    const unsigned short* sA_l = sA_h + 4096;
    const unsigned short* sB_h = sA_h + 8192;       // 16 chunks: rows 0..255
    const unsigned short* sB_l = sA_h + 16384;

    #pragma unroll
    for (int ks = 0; ks < 2; ++ks) {
      bf16x8 fah[2], fal[2], fbh[2], fbl[2];
      const int cb = ks * 2 + l5;                   // logical 8-short k-chunk
      #pragma unroll
      for (int i = 0; i < 2; ++i) {
        const int arow = wm * 64 + i * 32 + al31;
        const int aoff = arow * BK + ((cb ^ (arow & 3)) << 3);
        fah[i] = *(const bf16x8*)(sA_h + aoff);
        fal[i] = *(const bf16x8*)(sA_l + aoff);
        const int brow = wn * 64 + i * 32 + al31;
        const int boff = brow * BK + ((cb ^ (brow & 3)) << 3);
        fbh[i] = *(const bf16x8*)(sB_h + boff);
        fbl[i] = *(const bf16x8*)(sB_l + boff);
      }
      #pragma unroll
      for (int i = 0; i < 2; ++i)
        #pragma unroll
        for (int j = 0; j < 2; ++j) {
          acc[i][j] = __builtin_amdgcn_mfma_f32_32x32x16_bf16(fah[i], fbh[j], acc[i][j], 0, 0, 0);
          acc[i][j] = __builtin_amdgcn_mfma_f32_32x32x16_bf16(fah[i], fbl[j], acc[i][j], 0, 0, 0);
          acc[i][j] = __builtin_amdgcn_mfma_f32_32x32x16_bf16(fal[i], fbh[j], acc[i][j], 0, 0, 0);
        }
    }
    __syncthreads();                                // drains vmcnt + protects dbuf
    cur ^= 1;
  }

  if (MODE == 0) {
    // C/D 32x32 layout (m74/m101): col=lane&31, row=(reg&3)+8*(reg>>2)+4*(lane>>5)
    #pragma unroll
    for (int i = 0; i < 2; ++i) {
      const int rbase = r0 + wm * 64 + i * 32 + 4 * l5;
      #pragma unroll
      for (int j = 0; j < 2; ++j) {
        const int col = c0 + wn * 64 + j * 32 + al31;
        const float bz = bias[col];
        #pragma unroll
        for (int r = 0; r < 16; ++r) {
          const int row = rbase + (r & 3) + 8 * (r >> 2);
          float v = fmaxf(acc[i][j][r] + bz, 0.f);
          unsigned short hi = f2bf(v);
          Ch[(size_t)row * NOUT + col] = hi;
          Cl[(size_t)row * NOUT + col] = f2bf(v - bf2f(hi));
        }
      }
    }
  } else {
    // fused segment-max: 128-row tile never straddles graphs (4096%128==0)
    const int g = batch[r0];
    float* pb = (float*)lds;                        // reuse LDS (post-barrier)
    #pragma unroll
    for (int j = 0; j < 2; ++j) {
      const int colw = wn * 64 + j * 32 + al31;
      const float bz = bias[c0 + colw];
      float cm = 0.f;                               // relu floor
      #pragma unroll
      for (int i = 0; i < 2; ++i)
        #pragma unroll
        for (int r = 0; r < 16; ++r)
          cm = fmaxf(cm, acc[i][j][r] + bz);
      cm = fmaxf(cm, __shfl_xor(cm, 32));           // combine l5 row-halves
      if (l5 == 0) pb[wm * 256 + colw] = cm;
    }
    __syncthreads();
    if (tid < 256) {
      float m = fmaxf(pb[tid], pb[256 + tid]);
      atomicMax(pooled + (size_t)g * 1024 + c0 + tid, __float_as_uint(m));
    }
  }
}

// --- out[n] = cat(pooled[batch_skip[n]], x_skip[n]) -------------------------
__global__ void write_out(const float* __restrict__ pooled, const float* __restrict__ x_skip,
                          const int* __restrict__ batch_skip, float* __restrict__ out,
                          int N) {
  const int t = threadIdx.x;                        // 256
  for (int n = blockIdx.x; n < N; n += gridDim.x) {
    const int g = batch_skip[n];
    const float4* ps = (const float4*)(pooled + (size_t)g * 1024);
    float4* o = (float4*)(out + (size_t)n * 1280);
    o[t] = ps[t];                                   // 1024 floats (L2-hot)
    if (t < 64) {
      const float4* xs = (const float4*)(x_skip + (size_t)n * 256);
      o[256 + t] = xs[t];                           // 256 floats
    }
  }
}

extern "C" void kernel_launch(void* const* d_in, const int* in_sizes, int n_in,
                              void* d_out, int out_size, void* d_ws, size_t ws_size,
                              hipStream_t stream) {
  const float* x        = (const float*)d_in[0];
  const float* pos      = (const float*)d_in[1];
  const int*   batch    = (const int*)d_in[2];
  const float* x_skip   = (const float*)d_in[3];
  const int*   batch_sk = (const int*)d_in[5];
  const float* W1 = (const float*)d_in[6];
  const float* b1 = (const float*)d_in[7];
  const float* W2 = (const float*)d_in[8];
  const float* b2 = (const float*)d_in[9];
  const float* W3 = (const float*)d_in[10];
  const float* b3 = (const float*)d_in[11];
  float* out = (float*)d_out;

  // workspace (disjoint-lifetime aliasing; a1 dead before GEMM2 writes h2):
  //   h2h [0,64M) h2l [64M,128M) ; a1h [0,37.7M) a1l [40M,77.7M)
  //   h1h [128M,160M) h1l [160M,192M) ; weights+pooled at [192M,...)
  char* ws = (char*)d_ws;
  unsigned short* a1h = (unsigned short*)(ws);
  unsigned short* a1l = (unsigned short*)(ws + 41943040);
  unsigned short* h2h = (unsigned short*)(ws);
  unsigned short* h2l = (unsigned short*)(ws + 67108864);
  size_t off = 134217728;
  unsigned short* h1h = (unsigned short*)(ws + off); off += 33554432;
  unsigned short* h1l = (unsigned short*)(ws + off); off += 33554432;
  unsigned short* w1h = (unsigned short*)(ws + off); off += 147456;
  unsigned short* w1l = (unsigned short*)(ws + off); off += 147456;
  unsigned short* w2h = (unsigned short*)(ws + off); off += 262144;
  unsigned short* w2l = (unsigned short*)(ws + off); off += 262144;
  unsigned short* w3h = (unsigned short*)(ws + off); off += 1048576;
  unsigned short* w3l = (unsigned short*)(ws + off); off += 1048576;
  unsigned int*  pooled = (unsigned int*)(ws + off);             // 16*1024*4

  hipLaunchKernelGGL(pack_w, dim3(256),  dim3(288), 0, stream, W1, w1h, w1l, 259, 256);
  hipLaunchKernelGGL(pack_w, dim3(512),  dim3(256), 0, stream, W2, w2h, w2l, 256, 512);
  hipLaunchKernelGGL(pack_w, dim3(1024), dim3(512), 0, stream, W3, w3h, w3l, 512, 1024);
  hipLaunchKernelGGL(pack_a1, dim3(2048), dim3(256), 0, stream, x, pos, a1h, a1l);
  hipLaunchKernelGGL(zero_pool, dim3(16), dim3(1024), 0, stream, pooled);

  hipLaunchKernelGGL((gemm_split<288, 256, 0>), dim3(512), dim3(512), 0, stream,
                     a1h, a1l, w1h, w1l, b1, h1h, h1l,
                     (unsigned int*)nullptr, (const int*)nullptr);
  hipLaunchKernelGGL((gemm_split<256, 512, 0>), dim3(1024), dim3(512), 0, stream,
                     h1h, h1l, w2h, w2l, b2, h2h, h2l,
                     (unsigned int*)nullptr, (const int*)nullptr);
  hipLaunchKernelGGL((gemm_split<512, 1024, 1>), dim3(2048), dim3(512), 0, stream,
                     h2h, h2l, w3h, w3l, b3,
                     (unsigned short*)nullptr, (unsigned short*)nullptr, pooled, batch);

  hipLaunchKernelGGL(write_out, dim3(4096), dim3(256), 0, stream,
                     (const float*)pooled, x_skip, batch_sk, out, 65536);
}